// Round 5
// baseline (176.026 us; speedup 1.0000x reference)
//
#include <hip/hip_runtime.h>

// BarlowTwinsDiversityLoss: N=100000 nodes, K=8 heads, D=128.
// loss = mean_n [ sum_{k,l} (cc_nkl - delta_kl)^2 ],  cc = normalized Gram.
// Memory-bound (409.6 MB read once). Round-5:
//  - single fused kernel: last-finishing block reduces the 1563 partials
//    (atomic counter in ws, zeroed per-call via hipMemsetAsync; AGENT-scope
//    atomic loads for cross-XCD visibility). Saves 2nd launch + drain.
//  - explicit 2-deep load pipeline (va/vb, statically unrolled) so each
//    slice's 8 head-loads overlap the previous slice's 144 FMAs.
//  - NO vgpr cap (round 3 lesson: __launch_bounds__(.,4) -> 39 MB spill).

#define EPS 1e-8f

constexpr int D = 128;
constexpr int BLOCK = 256;            // 4 waves
constexpr int NODES_PER_BLOCK = 64;   // 4 lanes/node, 16 nodes/wave

__global__ __launch_bounds__(BLOCK) void btd_fused(
    const float* __restrict__ h0, const float* __restrict__ h1,
    const float* __restrict__ h2, const float* __restrict__ h3,
    const float* __restrict__ h4, const float* __restrict__ h5,
    const float* __restrict__ h6, const float* __restrict__ h7,
    float* __restrict__ ws, float* __restrict__ out,
    int n_nodes, int nblocks)
{
    unsigned* counter = (unsigned*)ws;      // ws[0..15] zeroed by memsetAsync
    float* partials = ws + 16;              // 64B-aligned partials array

    const int tid  = threadIdx.x;
    const int lane = tid & 63;
    const int wave = tid >> 6;
    const int g    = lane >> 2;
    const int l    = lane & 3;
    int node = blockIdx.x * NODES_PER_BLOCK + wave * 16 + g;
    const bool valid = (node < n_nodes);
    if (!valid) node = n_nodes - 1;         // clamped re-read; loss zeroed below

    float acc[36];
    #pragma unroll
    for (int i = 0; i < 36; ++i) acc[i] = 0.f;

    const unsigned base = (unsigned)node * D + l * 4;

    float4 va[8], vb[8];
    auto loadv = [&](float4* dst, int i) {
        const unsigned off = base + i * 16;
        dst[0] = *reinterpret_cast<const float4*>(h0 + off);
        dst[1] = *reinterpret_cast<const float4*>(h1 + off);
        dst[2] = *reinterpret_cast<const float4*>(h2 + off);
        dst[3] = *reinterpret_cast<const float4*>(h3 + off);
        dst[4] = *reinterpret_cast<const float4*>(h4 + off);
        dst[5] = *reinterpret_cast<const float4*>(h5 + off);
        dst[6] = *reinterpret_cast<const float4*>(h6 + off);
        dst[7] = *reinterpret_cast<const float4*>(h7 + off);
    };
    auto accv = [&](const float4* v) {
        int idx = 0;
        #pragma unroll
        for (int k = 0; k < 8; ++k) {
            #pragma unroll
            for (int m = k; m < 8; ++m) {
                acc[idx] += v[k].x * v[m].x + v[k].y * v[m].y
                          + v[k].z * v[m].z + v[k].w * v[m].w;
                ++idx;
            }
        }
    };

    // 2-deep pipeline over the 8 d-slices, fully static
    loadv(va, 0);
    loadv(vb, 1);
    accv(va);  loadv(va, 2);
    accv(vb);  loadv(vb, 3);
    accv(va);  loadv(va, 4);
    accv(vb);  loadv(vb, 5);
    accv(va);  loadv(va, 6);
    accv(vb);  loadv(vb, 7);
    accv(va);
    accv(vb);

    // butterfly sum across the node's 4 lanes
    #pragma unroll
    for (int i = 0; i < 36; ++i) {
        acc[i] += __shfl_xor(acc[i], 1, 64);
        acc[i] += __shfl_xor(acc[i], 2, 64);
    }

    // per-node loss (all 4 lanes redundantly; scale 0.25)
    float inv[8];
    float loss = 0.f;
    #pragma unroll
    for (int k = 0; k < 8; ++k) {
        const int dk = k * (17 - k) / 2;
        inv[k] = rsqrtf(fmaxf(acc[dk], EPS * EPS));
        const float dterm = acc[dk] * inv[k] * inv[k] - 1.0f;
        loss += dterm * dterm;
    }
    #pragma unroll
    for (int k = 0; k < 8; ++k) {
        #pragma unroll
        for (int m = k + 1; m < 8; ++m) {
            const float cc = acc[k * (17 - k) / 2 + (m - k)] * inv[k] * inv[m];
            loss += 2.0f * cc * cc;
        }
    }
    loss = valid ? loss * 0.25f : 0.f;

    // block reduction
    #pragma unroll
    for (int off = 32; off > 0; off >>= 1)
        loss += __shfl_down(loss, off, 64);

    __shared__ float smem[4];
    __shared__ int lastFlag;
    if (lane == 0) smem[wave] = loss;
    __syncthreads();
    if (tid == 0) {
        const float bsum = smem[0] + smem[1] + smem[2] + smem[3];
        __hip_atomic_store(&partials[blockIdx.x], bsum,
                           __ATOMIC_RELAXED, __HIP_MEMORY_SCOPE_AGENT);
        __threadfence();
        const unsigned old = atomicAdd(counter, 1u);
        lastFlag = (old == (unsigned)(nblocks - 1));
    }
    __syncthreads();

    if (lastFlag) {
        __threadfence();   // acquire: partials from all XCDs
        float s = 0.f;
        for (int i = tid; i < nblocks; i += BLOCK)
            s += __hip_atomic_load(&partials[i], __ATOMIC_RELAXED,
                                   __HIP_MEMORY_SCOPE_AGENT);
        #pragma unroll
        for (int off = 32; off > 0; off >>= 1)
            s += __shfl_down(s, off, 64);
        if (lane == 0) smem[wave] = s;
        __syncthreads();
        if (tid == 0)
            out[0] = (smem[0] + smem[1] + smem[2] + smem[3]) / (float)n_nodes;
    }
}

extern "C" void kernel_launch(void* const* d_in, const int* in_sizes, int n_in,
                              void* d_out, int out_size, void* d_ws, size_t ws_size,
                              hipStream_t stream) {
    const int n_nodes = in_sizes[0] / D;   // 100000
    const int nblocks = (n_nodes + NODES_PER_BLOCK - 1) / NODES_PER_BLOCK;  // 1563

    hipMemsetAsync(d_ws, 0, 64, stream);   // zero the arrival counter each call

    btd_fused<<<nblocks, BLOCK, 0, stream>>>(
        (const float*)d_in[0], (const float*)d_in[1],
        (const float*)d_in[2], (const float*)d_in[3],
        (const float*)d_in[4], (const float*)d_in[5],
        (const float*)d_in[6], (const float*)d_in[7],
        (float*)d_ws, (float*)d_out, n_nodes, nblocks);
}